// Round 1
// baseline (450.376 us; speedup 1.0000x reference)
//
#include <hip/hip_runtime.h>
#include <hip/hip_bf16.h>

#define C_CH 4096
#define D_DIM 128

// ---------------- sort-based path (atomic-free fp accumulation) ----------------

__global__ void init_kernel(int* cnt, int* first, int B) {
    int i = blockIdx.x * blockDim.x + threadIdx.x;
    if (i < C_CH) { cnt[i] = 0; first[i] = B - 1; }
}

__global__ void count_kernel(const int* __restrict__ ids, int* cnt, int* first, int B) {
    int i = blockIdx.x * blockDim.x + threadIdx.x;
    if (i < B) {
        int c = ids[i];
        atomicAdd(&cnt[c], 1);
        atomicMin(&first[c], i);
    }
}

// exclusive prefix sum over 4096 counts; one block of 1024 threads, 4 elems/thread
__global__ void scan_kernel(const int* __restrict__ cnt, int* offs, int* cursor) {
    __shared__ int wtot[16];
    int tid  = threadIdx.x;        // 0..1023
    int lane = tid & 63;
    int wave = tid >> 6;           // 0..15
    int base = tid * 4;
    int v0 = cnt[base + 0];
    int v1 = cnt[base + 1];
    int v2 = cnt[base + 2];
    int v3 = cnt[base + 3];
    int s = v0 + v1 + v2 + v3;
    int inc = s;
    // inclusive wave scan (64 lanes)
    for (int off = 1; off < 64; off <<= 1) {
        int n = __shfl_up(inc, off, 64);
        if (lane >= off) inc += n;
    }
    if (lane == 63) wtot[wave] = inc;
    __syncthreads();
    if (wave == 0) {
        int t = (lane < 16) ? wtot[lane] : 0;
        int ts = t;
        for (int off = 1; off < 16; off <<= 1) {
            int n = __shfl_up(ts, off, 64);
            if (lane >= off) ts += n;
        }
        if (lane < 16) wtot[lane] = ts - t;   // exclusive wave offsets
    }
    __syncthreads();
    int excl = wtot[wave] + (inc - s);        // exclusive offset for this thread's group
    int run = excl;
    offs[base + 0] = run; cursor[base + 0] = run; run += v0;
    offs[base + 1] = run; cursor[base + 1] = run; run += v1;
    offs[base + 2] = run; cursor[base + 2] = run; run += v2;
    offs[base + 3] = run; cursor[base + 3] = run; run += v3;
    if (tid == 1023) offs[C_CH] = run;        // == B
}

__global__ void scatter_kernel(const int* __restrict__ ids, int* cursor, int* order, int B) {
    int i = blockIdx.x * blockDim.x + threadIdx.x;
    if (i < B) {
        int c = ids[i];
        int pos = atomicAdd(&cursor[c], 1);
        order[pos] = i;
    }
}

// one block per channel, 128 threads; thread d owns column d. Coalesced 512B row reads.
__global__ __launch_bounds__(128) void reduce_kernel(
        const float* __restrict__ z, const int* __restrict__ order,
        const int* __restrict__ offs, const int* __restrict__ first,
        const int* __restrict__ y, float* __restrict__ out, int B) {
    int c = blockIdx.x;
    int d = threadIdx.x;
    int beg = offs[c];
    int end = offs[c + 1];
    float acc = 0.f;
    int r = beg;
    for (; r + 8 <= end; r += 8) {
        int i0 = order[r + 0], i1 = order[r + 1], i2 = order[r + 2], i3 = order[r + 3];
        int i4 = order[r + 4], i5 = order[r + 5], i6 = order[r + 6], i7 = order[r + 7];
        float a0 = z[(size_t)i0 * D_DIM + d];
        float a1 = z[(size_t)i1 * D_DIM + d];
        float a2 = z[(size_t)i2 * D_DIM + d];
        float a3 = z[(size_t)i3 * D_DIM + d];
        float a4 = z[(size_t)i4 * D_DIM + d];
        float a5 = z[(size_t)i5 * D_DIM + d];
        float a6 = z[(size_t)i6 * D_DIM + d];
        float a7 = z[(size_t)i7 * D_DIM + d];
        acc += ((a0 + a1) + (a2 + a3)) + ((a4 + a5) + (a6 + a7));
    }
    for (; r < end; ++r) acc += z[(size_t)order[r] * D_DIM + d];
    int cnt_c = end - beg;
    out[(size_t)c * D_DIM + d] = acc / (float)max(cnt_c, 1);
    if (d == 0) {
        int fi = first[c];                    // already clamped to <= B-1 by init
        out[(size_t)C_CH * D_DIM + c] = (float)y[fi];
    }
}

// ---------------- fallback path (ws too small): direct fp atomics into d_out ----------------

__global__ void f_init(float* out, int* cnt, int* first, int B, int n) {
    int i = blockIdx.x * blockDim.x + threadIdx.x;
    if (i < n) out[i] = 0.f;
    if (i < C_CH) { cnt[i] = 0; first[i] = B - 1; }
}

__global__ void f_scatter(const float* __restrict__ z, const int* __restrict__ ids,
                          float* out, int B) {
    int t = blockIdx.x * blockDim.x + threadIdx.x;   // one float4 per thread
    int row = t >> 5, q = t & 31;
    if (row < B) {
        float4 v = ((const float4*)z)[t];
        float* dst = out + (size_t)ids[row] * D_DIM + q * 4;
        unsafeAtomicAdd(dst + 0, v.x);
        unsafeAtomicAdd(dst + 1, v.y);
        unsafeAtomicAdd(dst + 2, v.z);
        unsafeAtomicAdd(dst + 3, v.w);
    }
}

__global__ void f_final(float* out, const int* __restrict__ cnt,
                        const int* __restrict__ first, const int* __restrict__ y) {
    int i = blockIdx.x * blockDim.x + threadIdx.x;
    if (i < C_CH * D_DIM) {
        int c = i >> 7;
        out[i] = out[i] / (float)max(cnt[c], 1);
    }
    if (i < C_CH) out[C_CH * D_DIM + i] = (float)y[first[i]];
}

// ---------------- launch ----------------

extern "C" void kernel_launch(void* const* d_in, const int* in_sizes, int n_in,
                              void* d_out, int out_size, void* d_ws, size_t ws_size,
                              hipStream_t stream) {
    const float* z  = (const float*)d_in[0];
    const int*   y  = (const int*)d_in[1];
    const int*   ids = (const int*)d_in[2];
    float* out = (float*)d_out;
    const int B = in_sizes[2];

    int* cnt    = (int*)d_ws;           // 4096
    int* offs   = cnt + C_CH;           // 4097 (+3 pad)
    int* cursor = offs + C_CH + 4;      // 4096
    int* first  = cursor + C_CH;        // 4096
    int* order  = first + C_CH;         // B
    size_t need = ((size_t)(C_CH * 4 + 4) + (size_t)B) * sizeof(int);

    if (ws_size >= need) {
        init_kernel<<<(C_CH + 255) / 256, 256, 0, stream>>>(cnt, first, B);
        count_kernel<<<(B + 255) / 256, 256, 0, stream>>>(ids, cnt, first, B);
        scan_kernel<<<1, 1024, 0, stream>>>(cnt, offs, cursor);
        scatter_kernel<<<(B + 255) / 256, 256, 0, stream>>>(ids, cursor, order, B);
        reduce_kernel<<<C_CH, 128, 0, stream>>>(z, order, offs, first, y, out, B);
    } else {
        int n = C_CH * D_DIM;
        f_init<<<(n + 255) / 256, 256, 0, stream>>>(out, cnt, first, B, n);
        count_kernel<<<(B + 255) / 256, 256, 0, stream>>>(ids, cnt, first, B);
        long long t = (long long)B * 32;
        f_scatter<<<(int)((t + 255) / 256), 256, 0, stream>>>(z, ids, out, B);
        f_final<<<(n + 255) / 256, 256, 0, stream>>>(out, cnt, first, y);
    }
}